// Round 4
// baseline (140.015 us; speedup 1.0000x reference)
//
#include <hip/hip_runtime.h>

// ---------------------------------------------------------------------------
// DeltaModel: B=256, L=2048, H=V=64.
//  (1) hs/k/v/q depend only on token id (V=64) -> 64-entry tables.
//  (2) r = M_N q -> backward scan with y_a = k_a . u for all 64 keys:
//        s = y[b_t];  y -= s * G[.][b_t];  r += s * v[b_t]
//      G[a][b] = k_a.k_b. Critical path = readlane -> fma.
//  (3) G,v packed float2 -> one ds_read_b64 per step. Prefetch depth 16
//      (2x16 float2 = 64 VGPRs) so the compiler can afford the double
//      buffer (R2's 64-deep buffers = 256 VGPRs were rescheduled away).
// ---------------------------------------------------------------------------

#define DPP_ADD_F32(x, ctrl, rm, bm, bc)                                      \
  (x) = (x) + __int_as_float(__builtin_amdgcn_update_dpp(                     \
            0, __float_as_int(x), (ctrl), (rm), (bm), (bc)))

__device__ __forceinline__ float wave_sum64(float x) {
  DPP_ADD_F32(x, 0x111, 0xf, 0xf, true);   // row_shr:1
  DPP_ADD_F32(x, 0x112, 0xf, 0xf, true);   // row_shr:2
  DPP_ADD_F32(x, 0x114, 0xf, 0xf, true);   // row_shr:4
  DPP_ADD_F32(x, 0x118, 0xf, 0xf, true);   // row_shr:8
  DPP_ADD_F32(x, 0x142, 0xa, 0xf, false);  // row_bcast:15
  DPP_ADD_F32(x, 0x143, 0xc, 0xf, false);  // row_bcast:31 -> lane 63 total
  return __int_as_float(__builtin_amdgcn_readlane(__float_as_int(x), 63));
}

__device__ __forceinline__ float readlane_f(float x, int lane) {
  return __int_as_float(__builtin_amdgcn_readlane(__float_as_int(x), lane));
}

// ---------------------------------------------------------------------------
// Kernel A: per-token tables k_n, v, q (weights staged in padded LDS).
// ---------------------------------------------------------------------------
__global__ __launch_bounds__(64) void build_tables(
    const float* __restrict__ embed, const float* __restrict__ W1,
    const float* __restrict__ b1, const float* __restrict__ W2,
    const float* __restrict__ b2, const float* __restrict__ gamma,
    const float* __restrict__ beta, const float* __restrict__ Wk,
    const float* __restrict__ Wv, const float* __restrict__ Wq,
    float* __restrict__ k_tab, float* __restrict__ v_tab,
    float* __restrict__ q_tab) {
  __shared__ float Wbuf[8448];
  __shared__ float e_s[64];
  __shared__ float f1_s[128];
  __shared__ float hs_s[64];
  const int tok = blockIdx.x;
  const int l = threadIdx.x;

  const float e = embed[tok * 64 + l];
  e_s[l] = e;
  for (int i = 0; i < 128; ++i) Wbuf[i * 65 + l] = W1[i * 64 + l];
  __syncthreads();

  float a0 = b1[l], a1 = b1[l + 64];
#pragma unroll
  for (int h = 0; h < 64; ++h) {
    a0 = fmaf(e_s[h], Wbuf[l * 65 + h], a0);
    a1 = fmaf(e_s[h], Wbuf[(l + 64) * 65 + h], a1);
  }
  f1_s[l] = fmaxf(a0, 0.f);
  f1_s[l + 64] = fmaxf(a1, 0.f);
  __syncthreads();

  for (int i = 0; i < 128; ++i)
    Wbuf[(i >> 1) * 131 + (i & 1) * 64 + l] = W2[i * 64 + l];
  __syncthreads();

  float acc = b2[l];
#pragma unroll
  for (int j = 0; j < 128; ++j) acc = fmaf(f1_s[j], Wbuf[l * 131 + j], acc);
  const float hval = e + acc;

  const float mu = wave_sum64(hval) * (1.f / 64.f);
  const float d = hval - mu;
  const float var = wave_sum64(d * d) * (1.f / 64.f);
  const float hs = d * (1.f / sqrtf(var + 1e-5f)) * gamma[l] + beta[l];
  hs_s[l] = hs;
  __syncthreads();

  for (int i = 0; i < 64; ++i) {
    Wbuf[i * 65 + l] = Wk[i * 64 + l];
    Wbuf[4224 + i * 65 + l] = Wv[i * 64 + l];
  }
  __syncthreads();
  float kk = 0.f, vv = 0.f;
#pragma unroll
  for (int h = 0; h < 64; ++h) {
    kk = fmaf(hs_s[h], Wbuf[l * 65 + h], kk);
    vv = fmaf(hs_s[h], Wbuf[4224 + l * 65 + h], vv);
  }
  __syncthreads();
  for (int i = 0; i < 64; ++i) Wbuf[i * 65 + l] = Wq[i * 64 + l];
  __syncthreads();
  float qq = 0.f;
#pragma unroll
  for (int h = 0; h < 64; ++h) qq = fmaf(hs_s[h], Wbuf[l * 65 + h], qq);

  float nrm = fmaxf(sqrtf(wave_sum64(kk * kk)), 1e-12f);
  k_tab[tok * 64 + l] = kk / nrm;
  v_tab[tok * 64 + l] = vv;
  q_tab[tok * 64 + l] = qq;
}

// ---------------------------------------------------------------------------
// Kernel B: GV[a][l] = {G[a][l], v[a][l]} packed float2; KQ[a][l] = q_a.k_l.
// ---------------------------------------------------------------------------
__global__ __launch_bounds__(64) void build_gram(
    const float* __restrict__ k_tab, const float* __restrict__ q_tab,
    const float* __restrict__ v_tab, float2* __restrict__ GV,
    float* __restrict__ KQ) {
  __shared__ float k_s[4160];
  __shared__ float q_s[64];
  const int a = blockIdx.x;
  const int l = threadIdx.x;
  for (int i = 0; i < 64; ++i) k_s[i * 65 + l] = k_tab[i * 64 + l];
  q_s[l] = q_tab[a * 64 + l];
  __syncthreads();
  float g = 0.f, kq = 0.f;
#pragma unroll
  for (int h = 0; h < 64; ++h) {
    g = fmaf(k_s[a * 65 + h], k_s[l * 65 + h], g);
    kq = fmaf(q_s[h], k_s[l * 65 + h], kq);
  }
  GV[a * 64 + l] = make_float2(g, v_tab[a * 64 + l]);
  KQ[a * 64 + l] = kq;
}

// ---------------------------------------------------------------------------
// Kernel C: per-batch scan + head. One wave per batch; lane a owns y_a.
// 64-step bodies, four 16-step sub-bodies; sub-body consumes one 16-slot
// register buffer while prefetching the next 16 columns into the other.
// ---------------------------------------------------------------------------
__global__ __launch_bounds__(64, 1) void scan_head(
    const int* __restrict__ seq, const float2* __restrict__ GVg,
    const float* __restrict__ KQ, const float* __restrict__ Wrp,
    const float* __restrict__ brp, const float* __restrict__ Wout,
    const float* __restrict__ bout, float* __restrict__ out) {
  __shared__ float2 GV_s[4160];  // 65 rows of 64 (row 64 = zeros, dummy tok)
  __shared__ float tmp[64];
  const int b = blockIdx.x;
  const int l = threadIdx.x;

#pragma unroll
  for (int i = 0; i < 32; ++i)
    ((float4*)GV_s)[l + 64 * i] = ((const float4*)GVg)[l + 64 * i];
  GV_s[4096 + l] = make_float2(0.f, 0.f);

  const int* tokp = seq + b * 2048;
  int tok_cur = tokp[2047 - l];       // body 0: slot j = lane, t = 2047-j
  int tok_nxt = tokp[2047 - 64 - l];  // body 1
  __syncthreads();

  const int qt = __builtin_amdgcn_readlane(tok_cur, 0);  // t=2047 token -> q
  float y = KQ[qt * 64 + l];                             // y_a = k_a . q
  float r = 0.f;
  if (l == 0) tok_cur = 64;  // slot 0 = dummy step (zero row)

  float2 bufA[16], bufB[16];
#pragma unroll
  for (int j = 0; j < 16; ++j) {  // prime: columns for steps 0..15
    const int bp = __builtin_amdgcn_readlane(tok_cur, j);
    bufA[j] = GV_s[bp * 64 + l];
  }

  // One 16-step sub-body: consume cons[j] (token tc lane cbase+j), prefetch
  // pref[j] for step pbase+j (token tp). Loads assigned directly into the
  // destination slot -> no copies; 64 VGPRs of buffer total.
  auto sub = [&](float2* cons, float2* pref, int tc, int cbase, int tp,
                 int pbase) {
#pragma unroll
    for (int j = 0; j < 16; ++j) {
      const int bp = __builtin_amdgcn_readlane(tp, pbase + j);
      const float2 gv = GV_s[bp * 64 + l];
      const int bc = __builtin_amdgcn_readlane(tc, cbase + j) & 63;
      const float s = readlane_f(y, bc);
      y = fmaf(-s, cons[j].x, y);
      r = fmaf(s, cons[j].y, r);
      pref[j] = gv;
    }
  };

  for (int n = 0; n < 32; ++n) {
    const int tok_fut = (n + 2 <= 31) ? tokp[2047 - 64 * (n + 2) - l] : 0;
    sub(bufA, bufB, tok_cur, 0, tok_cur, 16);
    sub(bufB, bufA, tok_cur, 16, tok_cur, 32);
    sub(bufA, bufB, tok_cur, 32, tok_cur, 48);
    sub(bufB, bufA, tok_cur, 48, tok_nxt, 0);  // last: prefetch next body
    tok_cur = tok_nxt;
    tok_nxt = tok_fut;
  }

  // Head: r -> Wrp -> Wout (weights staged padded into GV_s memory)
  float* Wb = (float*)GV_s;
  tmp[l] = r;
  for (int i = 0; i < 64; ++i) {
    Wb[i * 65 + l] = Wrp[i * 64 + l];
    Wb[4160 + i * 65 + l] = Wout[i * 64 + l];
  }
  __syncthreads();
  float acc = brp[l];
#pragma unroll
  for (int j = 0; j < 64; ++j) acc = fmaf(tmp[j], Wb[l * 65 + j], acc);
  __syncthreads();
  tmp[l] = acc;
  __syncthreads();
  float o = bout[l];
#pragma unroll
  for (int i = 0; i < 64; ++i) o = fmaf(tmp[i], Wb[4160 + l * 65 + i], o);
  out[b * 64 + l] = o;
}

extern "C" void kernel_launch(void* const* d_in, const int* in_sizes, int n_in,
                              void* d_out, int out_size, void* d_ws,
                              size_t ws_size, hipStream_t stream) {
  const int* seq = (const int*)d_in[0];
  const float* embed = (const float*)d_in[1];
  const float* W1 = (const float*)d_in[2];
  const float* b1 = (const float*)d_in[3];
  const float* W2 = (const float*)d_in[4];
  const float* b2 = (const float*)d_in[5];
  const float* gamma = (const float*)d_in[6];
  const float* beta = (const float*)d_in[7];
  const float* Wk = (const float*)d_in[8];
  const float* Wv = (const float*)d_in[9];
  const float* Wq = (const float*)d_in[10];
  const float* Wrp = (const float*)d_in[11];
  const float* brp = (const float*)d_in[12];
  const float* Wout = (const float*)d_in[13];
  const float* bout = (const float*)d_in[14];

  float* wsf = (float*)d_ws;
  float* k_tab = wsf;                   // 4096
  float* v_tab = wsf + 4096;            // 4096
  float* q_tab = wsf + 8192;            // 4096
  float2* GV = (float2*)(wsf + 12288);  // 4096 float2
  float* KQ = wsf + 20480;              // 4096

  build_tables<<<64, 64, 0, stream>>>(embed, W1, b1, W2, b2, gamma, beta, Wk,
                                      Wv, Wq, k_tab, v_tab, q_tab);
  build_gram<<<64, 64, 0, stream>>>(k_tab, q_tab, v_tab, GV, KQ);
  scan_head<<<256, 64, 0, stream>>>(seq, GV, KQ, Wrp, brp, Wout, bout,
                                    (float*)d_out);
}

// Round 5
// 137.905 us; speedup vs baseline: 1.0153x; 1.0153x over previous
//
#include <hip/hip_runtime.h>

// ---------------------------------------------------------------------------
// DeltaModel: B=256, L=2048, H=V=64.
//  (1) hs/k/v/q depend only on token id (V=64) -> 64-entry tables.
//  (2) r = M_N q -> backward scan with y_a = k_a . u for all 64 keys:
//        s = y[b_t];  y -= s * G[.][b_t];  r += s * v[b_t]
//      G[a][b] = k_a.k_b. Critical path = readlane -> fma.
//  (3) G,v packed float2, one ds_read_b64/step, depth-16 double buffer.
//      R2/R3 LESSON: buffers passed via pointers / oversized arrays fall to
//      scratch (VGPR_Count stayed 132, 40-55 cyc/step). Here buffers are
//      macro-substituted names with literal indices -> guaranteed SROA; lane
//      indices/prefetch tokens hoisted to SGPRs before each 16-step chain.
// ---------------------------------------------------------------------------

#define DPP_ADD_F32(x, ctrl, rm, bm, bc)                                      \
  (x) = (x) + __int_as_float(__builtin_amdgcn_update_dpp(                     \
            0, __float_as_int(x), (ctrl), (rm), (bm), (bc)))

__device__ __forceinline__ float wave_sum64(float x) {
  DPP_ADD_F32(x, 0x111, 0xf, 0xf, true);   // row_shr:1
  DPP_ADD_F32(x, 0x112, 0xf, 0xf, true);   // row_shr:2
  DPP_ADD_F32(x, 0x114, 0xf, 0xf, true);   // row_shr:4
  DPP_ADD_F32(x, 0x118, 0xf, 0xf, true);   // row_shr:8
  DPP_ADD_F32(x, 0x142, 0xa, 0xf, false);  // row_bcast:15
  DPP_ADD_F32(x, 0x143, 0xc, 0xf, false);  // row_bcast:31 -> lane 63 total
  return __int_as_float(__builtin_amdgcn_readlane(__float_as_int(x), 63));
}

__device__ __forceinline__ float readlane_f(float x, int lane) {
  return __int_as_float(__builtin_amdgcn_readlane(__float_as_int(x), lane));
}

// ---------------------------------------------------------------------------
// Kernel A: per-token tables k_n, v, q (weights staged in padded LDS).
// ---------------------------------------------------------------------------
__global__ __launch_bounds__(64) void build_tables(
    const float* __restrict__ embed, const float* __restrict__ W1,
    const float* __restrict__ b1, const float* __restrict__ W2,
    const float* __restrict__ b2, const float* __restrict__ gamma,
    const float* __restrict__ beta, const float* __restrict__ Wk,
    const float* __restrict__ Wv, const float* __restrict__ Wq,
    float* __restrict__ k_tab, float* __restrict__ v_tab,
    float* __restrict__ q_tab) {
  __shared__ float Wbuf[8448];
  __shared__ float e_s[64];
  __shared__ float f1_s[128];
  __shared__ float hs_s[64];
  const int tok = blockIdx.x;
  const int l = threadIdx.x;

  const float e = embed[tok * 64 + l];
  e_s[l] = e;
#pragma unroll 8
  for (int i = 0; i < 128; ++i) Wbuf[i * 65 + l] = W1[i * 64 + l];
  __syncthreads();

  float a0 = b1[l], a1 = b1[l + 64];
#pragma unroll
  for (int h = 0; h < 64; ++h) {
    a0 = fmaf(e_s[h], Wbuf[l * 65 + h], a0);
    a1 = fmaf(e_s[h], Wbuf[(l + 64) * 65 + h], a1);
  }
  f1_s[l] = fmaxf(a0, 0.f);
  f1_s[l + 64] = fmaxf(a1, 0.f);
  __syncthreads();

#pragma unroll 8
  for (int i = 0; i < 128; ++i)
    Wbuf[(i >> 1) * 131 + (i & 1) * 64 + l] = W2[i * 64 + l];
  __syncthreads();

  float acc = b2[l];
#pragma unroll
  for (int j = 0; j < 128; ++j) acc = fmaf(f1_s[j], Wbuf[l * 131 + j], acc);
  const float hval = e + acc;

  const float mu = wave_sum64(hval) * (1.f / 64.f);
  const float d = hval - mu;
  const float var = wave_sum64(d * d) * (1.f / 64.f);
  const float hs = d * (1.f / sqrtf(var + 1e-5f)) * gamma[l] + beta[l];
  hs_s[l] = hs;
  __syncthreads();

#pragma unroll 8
  for (int i = 0; i < 64; ++i) {
    Wbuf[i * 65 + l] = Wk[i * 64 + l];
    Wbuf[4224 + i * 65 + l] = Wv[i * 64 + l];
  }
  __syncthreads();
  float kk = 0.f, vv = 0.f;
#pragma unroll
  for (int h = 0; h < 64; ++h) {
    kk = fmaf(hs_s[h], Wbuf[l * 65 + h], kk);
    vv = fmaf(hs_s[h], Wbuf[4224 + l * 65 + h], vv);
  }
  __syncthreads();
#pragma unroll 8
  for (int i = 0; i < 64; ++i) Wbuf[i * 65 + l] = Wq[i * 64 + l];
  __syncthreads();
  float qq = 0.f;
#pragma unroll
  for (int h = 0; h < 64; ++h) qq = fmaf(hs_s[h], Wbuf[l * 65 + h], qq);

  float nrm = fmaxf(sqrtf(wave_sum64(kk * kk)), 1e-12f);
  k_tab[tok * 64 + l] = kk / nrm;
  v_tab[tok * 64 + l] = vv;
  q_tab[tok * 64 + l] = qq;
}

// ---------------------------------------------------------------------------
// Kernel B: GV[a][l] = {G[a][l], v[a][l]} packed float2; KQ[a][l] = q_a.k_l.
// ---------------------------------------------------------------------------
__global__ __launch_bounds__(64) void build_gram(
    const float* __restrict__ k_tab, const float* __restrict__ q_tab,
    const float* __restrict__ v_tab, float2* __restrict__ GV,
    float* __restrict__ KQ) {
  __shared__ float k_s[4160];
  __shared__ float q_s[64];
  const int a = blockIdx.x;
  const int l = threadIdx.x;
#pragma unroll 8
  for (int i = 0; i < 64; ++i) k_s[i * 65 + l] = k_tab[i * 64 + l];
  q_s[l] = q_tab[a * 64 + l];
  __syncthreads();
  float g = 0.f, kq = 0.f;
#pragma unroll
  for (int h = 0; h < 64; ++h) {
    g = fmaf(k_s[a * 65 + h], k_s[l * 65 + h], g);
    kq = fmaf(q_s[h], k_s[l * 65 + h], kq);
  }
  GV[a * 64 + l] = make_float2(g, v_tab[a * 64 + l]);
  KQ[a * 64 + l] = kq;
}

// ---------------------------------------------------------------------------
// Kernel C: per-batch scan + head. One wave per batch; lane a owns y_a.
// 16-step sub-bodies; CONS/PREF are macro-substituted register arrays.
// ---------------------------------------------------------------------------

// Consume CONS[0..15] (tokens = lanes CB..CB+15 of TC), prefetch PREF[0..15]
// (tokens = lanes PB..PB+15 of TP). All lane selects hoisted to SGPRs first;
// ds_reads issued before the consume chain (cover ~250 cyc > LDS latency).
#define SUB(CONS, PREF, TC, CB, TP, PB)                                       \
  {                                                                           \
    int bcs[16], bps[16];                                                     \
    _Pragma("unroll") for (int j = 0; j < 16; ++j) bcs[j] =                   \
        __builtin_amdgcn_readlane((TC), (CB) + j) & 63;                       \
    _Pragma("unroll") for (int j = 0; j < 16; ++j) bps[j] =                   \
        __builtin_amdgcn_readlane((TP), (PB) + j);                            \
    _Pragma("unroll") for (int j = 0; j < 16; ++j) PREF[j] =                  \
        GV_s[bps[j] * 64 + l];                                                \
    _Pragma("unroll") for (int j = 0; j < 16; ++j) {                          \
      const float s = readlane_f(y, bcs[j]);                                  \
      y = fmaf(-s, CONS[j].x, y);                                             \
      r = fmaf(s, CONS[j].y, r);                                              \
    }                                                                         \
  }

__global__ __launch_bounds__(64, 1) void scan_head(
    const int* __restrict__ seq, const float2* __restrict__ GVg,
    const float* __restrict__ KQ, const float* __restrict__ Wrp,
    const float* __restrict__ brp, const float* __restrict__ Wout,
    const float* __restrict__ bout, float* __restrict__ out) {
  __shared__ float2 GV_s[4160];  // 65 rows of 64 (row 64 = zeros, dummy tok)
  __shared__ float tmp[64];
  const int b = blockIdx.x;
  const int l = threadIdx.x;

#pragma unroll
  for (int i = 0; i < 32; ++i)
    ((float4*)GV_s)[l + 64 * i] = ((const float4*)GVg)[l + 64 * i];
  GV_s[4096 + l] = make_float2(0.f, 0.f);

  const int* tokp = seq + b * 2048;
  int tok_cur = tokp[2047 - l];       // body 0: slot j = lane, t = 2047-j
  int tok_nxt = tokp[2047 - 64 - l];  // body 1
  __syncthreads();

  const int qt = __builtin_amdgcn_readlane(tok_cur, 0);  // t=2047 token -> q
  float y = KQ[qt * 64 + l];                             // y_a = k_a . q
  float r = 0.f;
  if (l == 0) tok_cur = 64;  // slot 0 = dummy step (zero row)

  float2 bufA[16], bufB[16];
  {  // prime: columns for steps 0..15
    int bps[16];
#pragma unroll
    for (int j = 0; j < 16; ++j)
      bps[j] = __builtin_amdgcn_readlane(tok_cur, j);
#pragma unroll
    for (int j = 0; j < 16; ++j) bufA[j] = GV_s[bps[j] * 64 + l];
  }

  for (int n = 0; n < 32; ++n) {
    const int tok_fut = (n + 2 <= 31) ? tokp[2047 - 64 * (n + 2) - l] : 0;
    SUB(bufA, bufB, tok_cur, 0, tok_cur, 16);
    SUB(bufB, bufA, tok_cur, 16, tok_cur, 32);
    SUB(bufA, bufB, tok_cur, 32, tok_cur, 48);
    SUB(bufB, bufA, tok_cur, 48, tok_nxt, 0);  // last: prefetch next body
    tok_cur = tok_nxt;
    tok_nxt = tok_fut;
  }

  // Head: r -> Wrp -> Wout (weights staged padded into GV_s memory)
  float* Wb = (float*)GV_s;
  tmp[l] = r;
#pragma unroll 8
  for (int i = 0; i < 64; ++i) {
    Wb[i * 65 + l] = Wrp[i * 64 + l];
    Wb[4160 + i * 65 + l] = Wout[i * 64 + l];
  }
  __syncthreads();
  float acc = brp[l];
#pragma unroll
  for (int j = 0; j < 64; ++j) acc = fmaf(tmp[j], Wb[l * 65 + j], acc);
  __syncthreads();
  tmp[l] = acc;
  __syncthreads();
  float o = bout[l];
#pragma unroll
  for (int i = 0; i < 64; ++i) o = fmaf(tmp[i], Wb[4160 + l * 65 + i], o);
  out[b * 64 + l] = o;
}

extern "C" void kernel_launch(void* const* d_in, const int* in_sizes, int n_in,
                              void* d_out, int out_size, void* d_ws,
                              size_t ws_size, hipStream_t stream) {
  const int* seq = (const int*)d_in[0];
  const float* embed = (const float*)d_in[1];
  const float* W1 = (const float*)d_in[2];
  const float* b1 = (const float*)d_in[3];
  const float* W2 = (const float*)d_in[4];
  const float* b2 = (const float*)d_in[5];
  const float* gamma = (const float*)d_in[6];
  const float* beta = (const float*)d_in[7];
  const float* Wk = (const float*)d_in[8];
  const float* Wv = (const float*)d_in[9];
  const float* Wq = (const float*)d_in[10];
  const float* Wrp = (const float*)d_in[11];
  const float* brp = (const float*)d_in[12];
  const float* Wout = (const float*)d_in[13];
  const float* bout = (const float*)d_in[14];

  float* wsf = (float*)d_ws;
  float* k_tab = wsf;                   // 4096
  float* v_tab = wsf + 4096;            // 4096
  float* q_tab = wsf + 8192;            // 4096
  float2* GV = (float2*)(wsf + 12288);  // 4096 float2
  float* KQ = wsf + 20480;              // 4096

  build_tables<<<64, 64, 0, stream>>>(embed, W1, b1, W2, b2, gamma, beta, Wk,
                                      Wv, Wq, k_tab, v_tab, q_tab);
  build_gram<<<64, 64, 0, stream>>>(k_tab, q_tab, v_tab, GV, KQ);
  scan_head<<<256, 64, 0, stream>>>(seq, GV, KQ, Wrp, brp, Wout, bout,
                                    (float*)d_out);
}